// Round 1
// baseline (198.811 us; speedup 1.0000x reference)
//
#include <hip/hip_runtime.h>
#include <math.h>

// Problem constants (from reference)
#define RDIM 512
#define MDIM 4
#define LDIM 256
#define BDIM 8192
#define NF (RDIM / MDIM)            // 128
#define NROWS (BDIM * NF)           // 1048576 rows of m=4
#define SIGMA_EPS 1e-4f
#define LOG2E 1.4426950408889634f

#define BLOCK 256
#define ROWS_PER_THREAD 2
#define GRID (NROWS / (BLOCK * ROWS_PER_THREAD))   // 2048

// One thread processes ROWS_PER_THREAD rows (each row = 4 floats of z).
// Score simplification: softmax_l(-sig*dist) with dist = z2 - 2 z.c + c2;
// z2 is constant over l -> cancels. s_l = sig*(2 z.c_l - ||c_l||^2).
// In exp2 units: s2_l = sig2L * dot - sigL*||c_l||^2, sig2L = 2*sig*log2(e).
__global__ __launch_bounds__(BLOCK) void soft_quantize_kernel(
    const float4* __restrict__ x4,    // NROWS float4 (z rows)
    const float*  __restrict__ c,     // MDIM x LDIM, row-major (m*LDIM + l)
    const float*  __restrict__ sigma, // 1 element
    float4*       __restrict__ out4)  // NROWS float4
{
    __shared__ float4 sc[LDIM];   // {c0,c1,c2,c3} per center
    __shared__ float  snb[LDIM];  // -sig*log2e*||c_l||^2

    const int tid = threadIdx.x;

    const float sig   = fmaxf(sigma[0], 0.0f) + SIGMA_EPS;
    const float sigL  = sig * LOG2E;
    const float sig2L = 2.0f * sigL;

    if (tid < LDIM) {
        float c0 = c[0 * LDIM + tid];
        float c1 = c[1 * LDIM + tid];
        float c2 = c[2 * LDIM + tid];
        float c3 = c[3 * LDIM + tid];
        sc[tid] = make_float4(c0, c1, c2, c3);
        float csq = fmaf(c0, c0, fmaf(c1, c1, fmaf(c2, c2, c3 * c3)));
        snb[tid] = -sigL * csq;
    }
    __syncthreads();

    const int base = blockIdx.x * (BLOCK * ROWS_PER_THREAD) + tid;

    const float4 z0 = x4[base];
    const float4 z1 = x4[base + BLOCK];

    float  m0 = -INFINITY, m1 = -INFINITY;   // running max (exp2 domain)
    float  d0 = 0.0f,      d1 = 0.0f;        // running denom
    float4 a0 = make_float4(0.f, 0.f, 0.f, 0.f);
    float4 a1 = make_float4(0.f, 0.f, 0.f, 0.f);

    #pragma unroll 4
    for (int l = 0; l < LDIM; ++l) {
        const float4 cv = sc[l];    // broadcast b128, conflict-free
        const float  nb = snb[l];   // broadcast b32

        // ---- row 0 ----
        {
            float dot = fmaf(z0.x, cv.x, fmaf(z0.y, cv.y, fmaf(z0.z, cv.z, z0.w * cv.w)));
            float s   = fmaf(sig2L, dot, nb);
            float mn  = fmaxf(m0, s);
            float al  = __builtin_amdgcn_exp2f(m0 - mn);
            float e   = __builtin_amdgcn_exp2f(s - mn);
            d0   = fmaf(d0, al, e);
            a0.x = fmaf(a0.x, al, e * cv.x);
            a0.y = fmaf(a0.y, al, e * cv.y);
            a0.z = fmaf(a0.z, al, e * cv.z);
            a0.w = fmaf(a0.w, al, e * cv.w);
            m0 = mn;
        }
        // ---- row 1 ----
        {
            float dot = fmaf(z1.x, cv.x, fmaf(z1.y, cv.y, fmaf(z1.z, cv.z, z1.w * cv.w)));
            float s   = fmaf(sig2L, dot, nb);
            float mn  = fmaxf(m1, s);
            float al  = __builtin_amdgcn_exp2f(m1 - mn);
            float e   = __builtin_amdgcn_exp2f(s - mn);
            d1   = fmaf(d1, al, e);
            a1.x = fmaf(a1.x, al, e * cv.x);
            a1.y = fmaf(a1.y, al, e * cv.y);
            a1.z = fmaf(a1.z, al, e * cv.z);
            a1.w = fmaf(a1.w, al, e * cv.w);
            m1 = mn;
        }
    }

    const float inv0 = 1.0f / d0;
    const float inv1 = 1.0f / d1;
    out4[base]         = make_float4(a0.x * inv0, a0.y * inv0, a0.z * inv0, a0.w * inv0);
    out4[base + BLOCK] = make_float4(a1.x * inv1, a1.y * inv1, a1.z * inv1, a1.w * inv1);
}

extern "C" void kernel_launch(void* const* d_in, const int* in_sizes, int n_in,
                              void* d_out, int out_size, void* d_ws, size_t ws_size,
                              hipStream_t stream) {
    const float4* x4    = (const float4*)d_in[0];  // (B, R) fp32 = NROWS float4
    const float*  c     = (const float*)d_in[1];   // (M, L) fp32
    const float*  sigma = (const float*)d_in[2];   // (1,)  fp32
    float4*       out4  = (float4*)d_out;          // (B, R) fp32

    soft_quantize_kernel<<<GRID, BLOCK, 0, stream>>>(x4, c, sigma, out4);
}

// Round 2
// 138.371 us; speedup vs baseline: 1.4368x; 1.4368x over previous
//
#include <hip/hip_runtime.h>
#include <math.h>

// Problem constants (from reference)
#define RDIM 512
#define MDIM 4
#define LDIM 256
#define BDIM 8192
#define NF (RDIM / MDIM)            // 128
#define NROWS (BDIM * NF)           // 1048576 rows of m=4
#define SIGMA_EPS 1e-4f
#define LOG2E 1.4426950408889634f

#define BLOCK 256
#define RPT 4                        // rows per thread
#define CHUNK 8                      // centers per register-chunk
#define GRID (NROWS / (BLOCK * RPT)) // 1024

typedef float v2f __attribute__((ext_vector_type(2)));

static __device__ __forceinline__ v2f splat(float x) { v2f r; r.x = x; r.y = x; return r; }
static __device__ __forceinline__ v2f pk_fma(v2f a, v2f b, v2f c) { return __builtin_elementwise_fma(a, b, c); }
static __device__ __forceinline__ v2f pk_max(v2f a, v2f b) { return __builtin_elementwise_max(a, b); }
static __device__ __forceinline__ v2f exp2_pk(v2f v) {
    v2f r; r.x = __builtin_amdgcn_exp2f(v.x); r.y = __builtin_amdgcn_exp2f(v.y); return r;
}

// Score simplification: softmax_l(-sig*dist), dist = z2 - 2 z.c + c2; z2 cancels.
// exp2 domain: s_l = (2 sig log2e) * (z.c_l) - (sig log2e)*||c_l||^2
// z is prescaled by 2*sig*log2e; bias seeded into the 4-FMA dot chain.
// Two rows packed per v2f lane (v_pk_fma_f32); flash-style chunked softmax:
// exact max over each 8-center chunk, one global rescale per chunk.
__global__ __launch_bounds__(BLOCK, 4) void soft_quantize_kernel(
    const float4* __restrict__ x4,    // NROWS float4 (z rows)
    const float*  __restrict__ c,     // MDIM x LDIM row-major
    const float*  __restrict__ sigma, // 1 element
    float4*       __restrict__ out4)  // NROWS float4
{
    __shared__ float4 sc[LDIM];   // {c0,c1,c2,c3} per center
    __shared__ float  snb[LDIM];  // -sig*log2e*||c_l||^2

    const int tid = threadIdx.x;

    const float sig   = fmaxf(sigma[0], 0.0f) + SIGMA_EPS;
    const float sigL  = sig * LOG2E;
    const float sig2L = 2.0f * sigL;

    if (tid < LDIM) {
        float c0 = c[0 * LDIM + tid];
        float c1 = c[1 * LDIM + tid];
        float c2 = c[2 * LDIM + tid];
        float c3 = c[3 * LDIM + tid];
        sc[tid] = make_float4(c0, c1, c2, c3);
        float csq = fmaf(c0, c0, fmaf(c1, c1, fmaf(c2, c2, c3 * c3)));
        snb[tid] = -sigL * csq;
    }
    __syncthreads();

    const int base = blockIdx.x * (BLOCK * RPT) + tid;

    const float4 z0 = x4[base];
    const float4 z1 = x4[base + BLOCK];
    const float4 z2 = x4[base + 2 * BLOCK];
    const float4 z3 = x4[base + 3 * BLOCK];

    // pack rows (0,1) -> group A, (2,3) -> group B; prescale by sig2L
    v2f zxA, zyA, zzA, zwA, zxB, zyB, zzB, zwB;
    zxA.x = z0.x * sig2L; zxA.y = z1.x * sig2L;
    zyA.x = z0.y * sig2L; zyA.y = z1.y * sig2L;
    zzA.x = z0.z * sig2L; zzA.y = z1.z * sig2L;
    zwA.x = z0.w * sig2L; zwA.y = z1.w * sig2L;
    zxB.x = z2.x * sig2L; zxB.y = z3.x * sig2L;
    zyB.x = z2.y * sig2L; zyB.y = z3.y * sig2L;
    zzB.x = z2.z * sig2L; zzB.y = z3.z * sig2L;
    zwB.x = z2.w * sig2L; zwB.y = z3.w * sig2L;

    v2f mA = splat(-1e30f), mB = splat(-1e30f);
    v2f dA = splat(0.f),    dB = splat(0.f);
    v2f axA = splat(0.f), ayA = splat(0.f), azA = splat(0.f), awA = splat(0.f);
    v2f axB = splat(0.f), ayB = splat(0.f), azB = splat(0.f), awB = splat(0.f);

    for (int lc = 0; lc < LDIM; lc += CHUNK) {
        float4 cv[CHUNK];
        float  nb[CHUNK];
        #pragma unroll
        for (int j = 0; j < CHUNK; ++j) { cv[j] = sc[lc + j]; nb[j] = snb[lc + j]; }

        // ---- group A (rows 0,1) ----
        {
            v2f s[CHUNK];
            #pragma unroll
            for (int j = 0; j < CHUNK; ++j) {
                v2f t = pk_fma(zxA, splat(cv[j].x), splat(nb[j]));
                t     = pk_fma(zyA, splat(cv[j].y), t);
                t     = pk_fma(zzA, splat(cv[j].z), t);
                s[j]  = pk_fma(zwA, splat(cv[j].w), t);
            }
            v2f mc = pk_max(pk_max(pk_max(s[0], s[1]), pk_max(s[2], s[3])),
                            pk_max(pk_max(s[4], s[5]), pk_max(s[6], s[7])));
            v2f mn = pk_max(mA, mc);
            v2f al = exp2_pk(mA - mn);
            dA = dA * al; axA = axA * al; ayA = ayA * al; azA = azA * al; awA = awA * al;
            #pragma unroll
            for (int j = 0; j < CHUNK; ++j) {
                v2f e = exp2_pk(s[j] - mn);
                dA  = dA + e;
                axA = pk_fma(e, splat(cv[j].x), axA);
                ayA = pk_fma(e, splat(cv[j].y), ayA);
                azA = pk_fma(e, splat(cv[j].z), azA);
                awA = pk_fma(e, splat(cv[j].w), awA);
            }
            mA = mn;
        }
        // ---- group B (rows 2,3) ----
        {
            v2f s[CHUNK];
            #pragma unroll
            for (int j = 0; j < CHUNK; ++j) {
                v2f t = pk_fma(zxB, splat(cv[j].x), splat(nb[j]));
                t     = pk_fma(zyB, splat(cv[j].y), t);
                t     = pk_fma(zzB, splat(cv[j].z), t);
                s[j]  = pk_fma(zwB, splat(cv[j].w), t);
            }
            v2f mc = pk_max(pk_max(pk_max(s[0], s[1]), pk_max(s[2], s[3])),
                            pk_max(pk_max(s[4], s[5]), pk_max(s[6], s[7])));
            v2f mn = pk_max(mB, mc);
            v2f al = exp2_pk(mB - mn);
            dB = dB * al; axB = axB * al; ayB = ayB * al; azB = azB * al; awB = awB * al;
            #pragma unroll
            for (int j = 0; j < CHUNK; ++j) {
                v2f e = exp2_pk(s[j] - mn);
                dB  = dB + e;
                axB = pk_fma(e, splat(cv[j].x), axB);
                ayB = pk_fma(e, splat(cv[j].y), ayB);
                azB = pk_fma(e, splat(cv[j].z), azB);
                awB = pk_fma(e, splat(cv[j].w), awB);
            }
            mB = mn;
        }
    }

    const float i0 = 1.0f / dA.x, i1 = 1.0f / dA.y;
    const float i2 = 1.0f / dB.x, i3 = 1.0f / dB.y;
    out4[base]             = make_float4(axA.x * i0, ayA.x * i0, azA.x * i0, awA.x * i0);
    out4[base + BLOCK]     = make_float4(axA.y * i1, ayA.y * i1, azA.y * i1, awA.y * i1);
    out4[base + 2 * BLOCK] = make_float4(axB.x * i2, ayB.x * i2, azB.x * i2, awB.x * i2);
    out4[base + 3 * BLOCK] = make_float4(axB.y * i3, ayB.y * i3, azB.y * i3, awB.y * i3);
}

extern "C" void kernel_launch(void* const* d_in, const int* in_sizes, int n_in,
                              void* d_out, int out_size, void* d_ws, size_t ws_size,
                              hipStream_t stream) {
    const float4* x4    = (const float4*)d_in[0];  // (B, R) fp32 = NROWS float4
    const float*  c     = (const float*)d_in[1];   // (M, L) fp32
    const float*  sigma = (const float*)d_in[2];   // (1,)  fp32
    float4*       out4  = (float4*)d_out;          // (B, R) fp32

    soft_quantize_kernel<<<GRID, BLOCK, 0, stream>>>(x4, c, sigma, out4);
}